// Round 16
// baseline (180.874 us; speedup 1.0000x reference)
//
#include <hip/hip_runtime.h>

// 2-layer GCN: h1 = emb[x] @ W1; agg+b1+relu; @ W2; agg+b2.
// CSR built per-launch via two-level binned counting sort (no global atomics).
// R16 = R14 (best, 155.3us) + scanB fused into scanA via last-block-finalize
// (device atomic counter + threadfence; removes one launch boundary).
// R15's degree-sort + deeper unroll REGRESSED: at 75% occupancy the masked
// gathers it eliminated were latency-hidden, while its overheads (extra sort
// phase, perm indirection, de-coalesced writes) were on the critical path.

#define BS   256
#define BSBIG 1024        // hist/binscatter block size (16 waves)
#define NBLK 256          // blocks for hist/binscatter
#define BINSHIFT 8        // 256 nodes per bin
#define BIN  256
#define MAXBINS 512
#define BINCAP 4608       // LDS packed staging (mean bin = 4092, sigma ~64)

union H2 { int i; _Float16 h[2]; };

// ---- pass A: per-block histograms of dst bins (int4 reads, grid-stride) -----
__global__ __launch_bounds__(BSBIG) void k_hist(
    const int* __restrict__ dst, int E, int NBINS, int* __restrict__ histG) {
    __shared__ int h[MAXBINS];
    int t = threadIdx.x;
    for (int i = t; i < NBINS; i += BSBIG) h[i] = 0;
    __syncthreads();
    int E4 = E >> 2;
    const int4* d4 = (const int4*)dst;
    for (int i = blockIdx.x * BSBIG + t; i < E4; i += NBLK * BSBIG) {
        int4 d = d4[i];
        atomicAdd(&h[d.x >> BINSHIFT], 1);
        atomicAdd(&h[d.y >> BINSHIFT], 1);
        atomicAdd(&h[d.z >> BINSHIFT], 1);
        atomicAdd(&h[d.w >> BINSHIFT], 1);
    }
    if (blockIdx.x == 0 && t < (E & 3))
        atomicAdd(&h[dst[(E4 << 2) + t] >> BINSHIFT], 1);
    __syncthreads();
    for (int i = t; i < NBINS; i += BSBIG) histG[i * NBLK + blockIdx.x] = h[i];
}

// ---- hierarchical exclusive scan over L = NBINS*NBLK ints -------------------
// scanB fused: the LAST block to finish scans the block sums into boff.
__global__ void k_scanA(const int* __restrict__ in, int L,
                        int* __restrict__ partial, int* __restrict__ bsum,
                        int* __restrict__ boff, int* __restrict__ counter) {
    __shared__ int s[BS];
    __shared__ int isLast;
    int t = threadIdx.x;
    int i = blockIdx.x * BS + t;
    int v = (i < L) ? in[i] : 0;
    s[t] = v;
    __syncthreads();
    for (int off = 1; off < BS; off <<= 1) {
        int add = (t >= off) ? s[t - off] : 0;
        __syncthreads();
        s[t] += add;
        __syncthreads();
    }
    if (i < L) partial[i] = s[t] - v;
    if (t == BS - 1) bsum[blockIdx.x] = s[BS - 1];
    // last-block finalize (scanB body)
    __threadfence();
    if (t == 0) isLast = (atomicAdd(counter, 1) == (int)gridDim.x - 1);
    __syncthreads();
    if (!isLast) return;
    int nB = gridDim.x;
    int PER = (nB + BS - 1) / BS;
    int loc[8];
    int base = t * PER;
    int sum = 0;
    for (int j = 0; j < PER && j < 8; j++) {
        int idx = base + j;
        int vv = (idx < nB) ? bsum[idx] : 0;
        loc[j] = sum;
        sum += vv;
    }
    __syncthreads();
    s[t] = sum;
    __syncthreads();
    for (int off = 1; off < BS; off <<= 1) {
        int add = (t >= off) ? s[t - off] : 0;
        __syncthreads();
        s[t] += add;
        __syncthreads();
    }
    int ex = s[t] - sum;
    for (int j = 0; j < PER && j < 8; j++) {
        int idx = base + j;
        if (idx < nB) boff[idx] = ex + loc[j];
    }
}

// ---- pass C: scatter edges into bin-partitioned order (LDS cursors only) ----
// ONE packed 4B write per edge: src | dstLocal<<18  (src < 2^18).
__global__ __launch_bounds__(BSBIG) void k_binscatter(
    const int* __restrict__ src, const int* __restrict__ dst,
    int E, int NBINS, const int* __restrict__ partial,
    const int* __restrict__ boff, int* __restrict__ packed) {
    __shared__ int cur[MAXBINS];
    int t = threadIdx.x;
    for (int i = t; i < NBINS; i += BSBIG)
        cur[i] = partial[i * NBLK + blockIdx.x] + boff[i];
    __syncthreads();
    int E4 = E >> 2;
    const int4* s4 = (const int4*)src;
    const int4* d4 = (const int4*)dst;
    for (int i = blockIdx.x * BSBIG + t; i < E4; i += NBLK * BSBIG) {
        int4 s = s4[i];
        int4 d = d4[i];
        int p0 = atomicAdd(&cur[d.x >> BINSHIFT], 1);
        packed[p0] = s.x | ((d.x & (BIN - 1)) << 18);
        int p1 = atomicAdd(&cur[d.y >> BINSHIFT], 1);
        packed[p1] = s.y | ((d.y & (BIN - 1)) << 18);
        int p2 = atomicAdd(&cur[d.z >> BINSHIFT], 1);
        packed[p2] = s.z | ((d.z & (BIN - 1)) << 18);
        int p3 = atomicAdd(&cur[d.w >> BINSHIFT], 1);
        packed[p3] = s.w | ((d.w & (BIN - 1)) << 18);
    }
    if (blockIdx.x == 0 && t < (E & 3)) {
        int e = (E4 << 2) + t;
        int d = dst[e];
        int p = atomicAdd(&cur[d >> BINSHIFT], 1);
        packed[p] = src[e] | ((d & (BIN - 1)) << 18);
    }
}

// ---- pass D: per-bin counting sort (staged in LDS) + fused mm1 --------------
__global__ void k_binsort(const int* __restrict__ packed,
                          const int* __restrict__ partial, const int* __restrict__ boff,
                          int NBINS, int N, int E,
                          const int* __restrict__ x, const float* __restrict__ emb,
                          const float* __restrict__ W1,
                          int* __restrict__ row_start, float* __restrict__ dinv,
                          int* __restrict__ col, _Float16* __restrict__ sig1) {
    __shared__ int buf[BINCAP];                  // 18 KB staging
    __shared__ int ldeg[BIN];
    __shared__ int lrs[BIN];
    __shared__ int cur[BIN];
    __shared__ float sW[512];                    // W1 (16x32)
    int b = blockIdx.x;
    int t = threadIdx.x;
    int node0 = b << BINSHIFT;
    int e0 = partial[b * NBLK] + boff[b];
    int e1 = (b + 1 < NBINS) ? (partial[(b + 1) * NBLK] + boff[b + 1]) : E;
    int cnt = e1 - e0;
    bool fits = (cnt <= BINCAP);                 // uniform per block
    if (b == 0 && t == 0) row_start[N] = E;      // sentinel
    sW[t] = W1[t];
    sW[t + 256] = W1[t + 256];
    ldeg[t] = 0;
    if (fits)
        for (int i = t; i < cnt; i += BS) buf[i] = packed[e0 + i];
    __syncthreads();
    for (int i = t; i < cnt; i += BS) {
        int v = fits ? buf[i] : packed[e0 + i];
        atomicAdd(&ldeg[((unsigned)v >> 18) & (BIN - 1)], 1);
    }
    __syncthreads();
    lrs[t] = ldeg[t];
    __syncthreads();
    for (int off = 1; off < BIN; off <<= 1) {
        int add = (t >= off) ? lrs[t - off] : 0;
        __syncthreads();
        lrs[t] += add;
        __syncthreads();
    }
    int myDeg = ldeg[t];
    int ex = lrs[t] - myDeg;
    cur[t] = ex;
    int n = node0 + t;                           // one node per thread
    float di = rsqrtf((float)(myDeg + 1));
    if (n < N) {
        row_start[n] = e0 + ex;
        dinv[n] = di;
    }
    __syncthreads();
    for (int i = t; i < cnt; i += BS) {
        int v = fits ? buf[i] : packed[e0 + i];
        int pos = atomicAdd(&cur[((unsigned)v >> 18) & (BIN - 1)], 1);
        col[e0 + pos] = v & 0x3FFFF;
    }
    // ---- fused mm1 for this bin's 256 nodes ----
    if (n < N) {
        const float4* er = (const float4*)(emb + (size_t)x[n] * 16);
        float4 ra = er[0], rb = er[1], rc = er[2], rd = er[3];
        float ev[16] = {ra.x, ra.y, ra.z, ra.w, rb.x, rb.y, rb.z, rb.w,
                        rc.x, rc.y, rc.z, rc.w, rd.x, rd.y, rd.z, rd.w};
        int4* s1o = (int4*)sig1;
        #pragma unroll
        for (int cq = 0; cq < 4; cq++) {
            H2 pk[4];
            #pragma unroll
            for (int dw = 0; dw < 4; dw++) {
                int c = cq * 8 + dw * 2;
                float acc0 = 0.f, acc1 = 0.f;
                #pragma unroll
                for (int k = 0; k < 16; k++) {
                    acc0 += ev[k] * sW[k * 32 + c];
                    acc1 += ev[k] * sW[k * 32 + c + 1];
                }
                pk[dw].h[0] = (_Float16)(acc0 * di);
                pk[dw].h[1] = (_Float16)(acc1 * di);
            }
            int4 pv;
            pv.x = pk[0].i; pv.y = pk[1].i; pv.z = pk[2].i; pv.w = pk[3].i;
            s1o[(size_t)n * 4 + cq] = pv;
        }
    }
}

// ---- fused layer-1 aggregate + b1 + relu + GEMM W2 -> sig2 (fp16) -----------
// 4 NODES per wave: lane = (node g in [0,4)) x (dword-channel cd in [0,16)).
// col prefetched one iteration ahead (overlaps next col load with gathers).
__global__ __launch_bounds__(BS) void k_agg1mm2(
    const _Float16* __restrict__ sig1, const int* __restrict__ row_start,
    const float* __restrict__ dinv, const int* __restrict__ col,
    const float* __restrict__ b1, const float* __restrict__ W2,
    int N, _Float16* __restrict__ sig2) {
    __shared__ float hbuf[4][4][36];   // [wave][node][32 ch + pad]
    int t = threadIdx.x;
    int lane = t & 63;
    int wid = t >> 6;
    int g  = lane >> 4;                // node within wave
    int cd = lane & 15;                // dword channel (2 fp16)
    int n = blockIdx.x * 16 + wid * 4 + g;
    int nld = (n < N) ? n : N - 1;
    int rs = row_start[nld];
    int re = row_start[nld + 1];
    int dn = (n < N) ? (re - rs) : 0;
    int dnm1 = (dn > 0) ? dn - 1 : 0;
    int dm = dn;                       // wave max degree
    dm = max(dm, __shfl_xor(dm, 16));
    dm = max(dm, __shfl_xor(dm, 32));
    float w2c[32];
    #pragma unroll
    for (int k = 0; k < 32; k++) w2c[k] = W2[k * 16 + cd];
    const int* s1i = (const int*)sig1;
    float a0 = 0.f, a1 = 0.f;
    int iters = (dm + 3) >> 2;
    int slot = cd & 3;
    int bidx = lane & 48;              // group base lane
    int colv = 0;
    if (iters > 0) {
        int idx = slot; if (idx > dnm1) idx = dnm1;
        colv = col[rs + idx];
    }
    for (int it = 0; it < iters; it++) {
        int e = it << 2;
        int coln = 0;
        if (it + 1 < iters) {
            int idx = e + 4 + slot; if (idx > dnm1) idx = dnm1;
            coln = col[rs + idx];      // prefetch next round
        }
        int s0 = __shfl(colv, bidx + 0);
        int s1 = __shfl(colv, bidx + 1);
        int s2 = __shfl(colv, bidx + 2);
        int s3 = __shfl(colv, bidx + 3);
        int u0 = s1i[s0 * 16 + cd];    // 4 rows (64B lines) per inst
        int u1 = s1i[s1 * 16 + cd];
        int u2 = s1i[s2 * 16 + cd];
        int u3 = s1i[s3 * 16 + cd];
        u0 = (e + 0 < dn) ? u0 : 0;    // 0x0 == +0.0 fp16 pair
        u1 = (e + 1 < dn) ? u1 : 0;
        u2 = (e + 2 < dn) ? u2 : 0;
        u3 = (e + 3 < dn) ? u3 : 0;
        H2 p0, p1, p2, p3;
        p0.i = u0; p1.i = u1; p2.i = u2; p3.i = u3;
        a0 += ((float)p0.h[0] + (float)p1.h[0]) + ((float)p2.h[0] + (float)p3.h[0]);
        a1 += ((float)p0.h[1] + (float)p1.h[1]) + ((float)p2.h[1] + (float)p3.h[1]);
        colv = coln;
    }
    {   // self-loop (pre-scaled row)
        H2 p; p.i = s1i[nld * 16 + cd];
        a0 += (float)p.h[0];
        a1 += (float)p.h[1];
    }
    float di = dinv[nld];
    float2 b = ((const float2*)b1)[cd];
    float h0 = fmaxf(a0 * di + b.x, 0.f);
    float h1 = fmaxf(a1 * di + b.y, 0.f);
    float* hb = hbuf[wid][g];
    *(float2*)&hb[2 * cd] = make_float2(h0, h1);
    // same-wave LDS produce->consume: in-order ds ops + lgkmcnt, no barrier
    float a = 0.f;
    #pragma unroll
    for (int k = 0; k < 32; k += 4) {
        float4 hv = *(const float4*)&hb[k];
        a = fmaf(hv.x, w2c[k],     a);
        a = fmaf(hv.y, w2c[k + 1], a);
        a = fmaf(hv.z, w2c[k + 2], a);
        a = fmaf(hv.w, w2c[k + 3], a);
    }
    if (n < N) sig2[(size_t)n * 16 + cd] = (_Float16)(a * di);   // pre-scale
}

// ---- layer-2 aggregate + b2 -> out ------------------------------------------
// 4 NODES per wave: lane = (node g) x (edge-half e2) x (dword cd in [0,8)).
__global__ __launch_bounds__(BS) void k_agg2(
    const _Float16* __restrict__ sig2, const int* __restrict__ row_start,
    const float* __restrict__ dinv, const int* __restrict__ col,
    const float* __restrict__ b2, int N, float* __restrict__ out) {
    int t = threadIdx.x;
    int lane = t & 63;
    int g  = lane >> 4;                // node within wave
    int e2 = (lane >> 3) & 1;          // edge half
    int cd = lane & 7;                 // dword channel (2 fp16)
    int n = blockIdx.x * 16 + (t >> 6) * 4 + g;
    int nld = (n < N) ? n : N - 1;
    int rs = row_start[nld];
    int re = row_start[nld + 1];
    int dn = (n < N) ? (re - rs) : 0;
    int dnm1 = (dn > 0) ? dn - 1 : 0;
    int dm = dn;
    dm = max(dm, __shfl_xor(dm, 16));
    dm = max(dm, __shfl_xor(dm, 32));
    const int* s2i = (const int*)sig2;
    float a0 = 0.f, a1 = 0.f;
    int iters = (dm + 7) >> 3;
    int slot = lane & 7;               // this lane's col slot (0..7)
    int bidx = lane & 48;
    int colv = 0;
    if (iters > 0) {
        int idx = slot; if (idx > dnm1) idx = dnm1;
        colv = col[rs + idx];
    }
    for (int it = 0; it < iters; it++) {
        int e = it << 3;
        int coln = 0;
        if (it + 1 < iters) {
            int idx = e + 8 + slot; if (idx > dnm1) idx = dnm1;
            coln = col[rs + idx];      // prefetch next round
        }
        #pragma unroll
        for (int j = 0; j < 4; j++) {
            int sl = 2 * j + e2;
            int sv = __shfl(colv, bidx + sl);
            int u = s2i[sv * 8 + cd];  // 8 rows (32B) per inst
            u = (e + sl < dn) ? u : 0;
            H2 p; p.i = u;
            a0 += (float)p.h[0];
            a1 += (float)p.h[1];
        }
        colv = coln;
    }
    a0 += __shfl_xor(a0, 8);           // combine edge halves
    a1 += __shfl_xor(a1, 8);
    {   // self-loop
        H2 p; p.i = s2i[nld * 8 + cd];
        a0 += (float)p.h[0];
        a1 += (float)p.h[1];
    }
    if (n < N && e2 == 0) {
        float di = dinv[nld];
        float2 b = ((const float2*)b2)[cd];
        float2 o;
        o.x = a0 * di + b.x;
        o.y = a1 * di + b.y;
        ((float2*)out)[(size_t)n * 8 + cd] = o;
    }
}

extern "C" void kernel_launch(void* const* d_in, const int* in_sizes, int n_in,
                              void* d_out, int out_size, void* d_ws, size_t ws_size,
                              hipStream_t stream) {
    const int*   x   = (const int*)d_in[0];
    const int*   ei  = (const int*)d_in[1];
    const float* emb = (const float*)d_in[2];
    const float* W1  = (const float*)d_in[3];
    const float* b1  = (const float*)d_in[4];
    const float* W2  = (const float*)d_in[5];
    const float* b2  = (const float*)d_in[6];
    float* out = (float*)d_out;

    const int N = in_sizes[0];
    const int E = in_sizes[1] / 2;
    const int* srcp = ei;
    const int* dstp = ei + E;
    const int NBINS = (N + BIN - 1) >> BINSHIFT;   // 391 for N=100000
    const int L = NBINS * NBLK;
    const int nB2 = (L + BS - 1) / BS;             // == NBINS

    auto al = [](size_t b) { return (b + 255) & ~size_t(255); };
    char* w = (char*)d_ws;
    auto carve = [&](size_t bytes) {
        void* p = (void*)w;
        w += al(bytes);
        return p;
    };
    // no unions: binsort writes sig1 while other blocks still read packed.
    int*   row_start = (int*)carve((size_t)(N + 1) * 4);
    float* dinv      = (float*)carve((size_t)N * 4);
    int*   col       = (int*)carve((size_t)(E + 256) * 4);  // +pad for clamped reads
    int*   histG     = (int*)carve((size_t)L * 4);
    int*   partial   = (int*)carve((size_t)L * 4);
    int*   bsum      = (int*)carve((size_t)nB2 * 4);
    int*   boff      = (int*)carve((size_t)nB2 * 4);
    int*   counter   = (int*)carve(256);
    int*   packed    = (int*)carve((size_t)E * 4);
    _Float16* sig1   = (_Float16*)carve((size_t)N * 32 * 2);
    _Float16* sig2   = (_Float16*)carve((size_t)N * 16 * 2);
    (void)ws_size; (void)n_in; (void)out_size;

    hipMemsetAsync(counter, 0, 4, stream);       // last-block-finalize flag

    int gL = (L + BS - 1) / BS;
    k_hist<<<NBLK, BSBIG, 0, stream>>>(dstp, E, NBINS, histG);
    k_scanA<<<gL, BS, 0, stream>>>(histG, L, partial, bsum, boff, counter);
    k_binscatter<<<NBLK, BSBIG, 0, stream>>>(srcp, dstp, E, NBINS, partial, boff,
                                             packed);
    k_binsort<<<NBINS, BS, 0, stream>>>(packed, partial, boff, NBINS, N, E,
                                        x, emb, W1, row_start, dinv, col, sig1);

    int gA = (N + 15) / 16;            // 4 waves x 4 nodes per block
    k_agg1mm2<<<gA, BS, 0, stream>>>(sig1, row_start, dinv, col, b1, W2, N, sig2);
    k_agg2<<<gA, BS, 0, stream>>>(sig2, row_start, dinv, col, b2, N, out);
}

// Round 17
// 156.402 us; speedup vs baseline: 1.1565x; 1.1565x over previous
//
#include <hip/hip_runtime.h>

// 2-layer GCN: h1 = emb[x] @ W1; agg+b1+relu; @ W2; agg+b2.
// CSR built per-launch via two-level binned counting sort (no global atomics).
// R17 = exact revert to R14 (best, 155.3us):
//   - int4 edge reads, 256-node bins, packed src|dstl<<18 (one 4B write/edge)
//   - 1024-thread hist/binscatter blocks (16 waves/CU latency hiding)
//   - binsort stages bin in LDS + fused mm1 (sig1 = dinv*h1 @ W1, fp16)
//   - agg kernels: 4 nodes/wave, lane = node x channel (no reductions),
//     4-rows-per-gather-inst, col prefetch, in-wave LDS GEMM epilogue.
// Rejected by measurement: LDS-atomic edge-parallel agg (R3, 3.6x regress);
// 16B-per-lane gathers (R10, burst divergence + VALU); channel-split passes
// (R7, new DRAM round-trips); cooperative fused build (R13, 4 waves/CU cap);
// degree-sorted scheduling (R15, off-critical-path win, on-path cost);
// atomic-counter scan fusion (R16, device fence flushes per-XCD L2).

#define BS   256
#define BSBIG 1024        // hist/binscatter block size (16 waves)
#define NBLK 256          // blocks for hist/binscatter
#define BINSHIFT 8        // 256 nodes per bin
#define BIN  256
#define MAXBINS 512
#define BINCAP 4608       // LDS packed staging (mean bin = 4092, sigma ~64)

union H2 { int i; _Float16 h[2]; };

// ---- pass A: per-block histograms of dst bins (int4 reads, grid-stride) -----
__global__ __launch_bounds__(BSBIG) void k_hist(
    const int* __restrict__ dst, int E, int NBINS, int* __restrict__ histG) {
    __shared__ int h[MAXBINS];
    int t = threadIdx.x;
    for (int i = t; i < NBINS; i += BSBIG) h[i] = 0;
    __syncthreads();
    int E4 = E >> 2;
    const int4* d4 = (const int4*)dst;
    for (int i = blockIdx.x * BSBIG + t; i < E4; i += NBLK * BSBIG) {
        int4 d = d4[i];
        atomicAdd(&h[d.x >> BINSHIFT], 1);
        atomicAdd(&h[d.y >> BINSHIFT], 1);
        atomicAdd(&h[d.z >> BINSHIFT], 1);
        atomicAdd(&h[d.w >> BINSHIFT], 1);
    }
    if (blockIdx.x == 0 && t < (E & 3))
        atomicAdd(&h[dst[(E4 << 2) + t] >> BINSHIFT], 1);
    __syncthreads();
    for (int i = t; i < NBINS; i += BSBIG) histG[i * NBLK + blockIdx.x] = h[i];
}

// ---- hierarchical exclusive scan over L = NBINS*NBLK ints -------------------
__global__ void k_scanA(const int* __restrict__ in, int L,
                        int* __restrict__ partial, int* __restrict__ bsum) {
    __shared__ int s[BS];
    int t = threadIdx.x;
    int i = blockIdx.x * BS + t;
    int v = (i < L) ? in[i] : 0;
    s[t] = v;
    __syncthreads();
    for (int off = 1; off < BS; off <<= 1) {
        int add = (t >= off) ? s[t - off] : 0;
        __syncthreads();
        s[t] += add;
        __syncthreads();
    }
    if (i < L) partial[i] = s[t] - v;
    if (t == BS - 1) bsum[blockIdx.x] = s[BS - 1];
}

__global__ void k_scanB(const int* __restrict__ bsum, int nB, int* __restrict__ boff) {
    __shared__ int s[BS];
    int t = threadIdx.x;
    int PER = (nB + BS - 1) / BS;
    int loc[8];
    int base = t * PER;
    int sum = 0;
    for (int j = 0; j < PER && j < 8; j++) {
        int idx = base + j;
        int v = (idx < nB) ? bsum[idx] : 0;
        loc[j] = sum;
        sum += v;
    }
    s[t] = sum;
    __syncthreads();
    for (int off = 1; off < BS; off <<= 1) {
        int add = (t >= off) ? s[t - off] : 0;
        __syncthreads();
        s[t] += add;
        __syncthreads();
    }
    int ex = s[t] - sum;
    for (int j = 0; j < PER && j < 8; j++) {
        int idx = base + j;
        if (idx < nB) boff[idx] = ex + loc[j];
    }
}

// ---- pass C: scatter edges into bin-partitioned order (LDS cursors only) ----
// ONE packed 4B write per edge: src | dstLocal<<18  (src < 2^18).
__global__ __launch_bounds__(BSBIG) void k_binscatter(
    const int* __restrict__ src, const int* __restrict__ dst,
    int E, int NBINS, const int* __restrict__ partial,
    const int* __restrict__ boff, int* __restrict__ packed) {
    __shared__ int cur[MAXBINS];
    int t = threadIdx.x;
    for (int i = t; i < NBINS; i += BSBIG)
        cur[i] = partial[i * NBLK + blockIdx.x] + boff[i];
    __syncthreads();
    int E4 = E >> 2;
    const int4* s4 = (const int4*)src;
    const int4* d4 = (const int4*)dst;
    for (int i = blockIdx.x * BSBIG + t; i < E4; i += NBLK * BSBIG) {
        int4 s = s4[i];
        int4 d = d4[i];
        int p0 = atomicAdd(&cur[d.x >> BINSHIFT], 1);
        packed[p0] = s.x | ((d.x & (BIN - 1)) << 18);
        int p1 = atomicAdd(&cur[d.y >> BINSHIFT], 1);
        packed[p1] = s.y | ((d.y & (BIN - 1)) << 18);
        int p2 = atomicAdd(&cur[d.z >> BINSHIFT], 1);
        packed[p2] = s.z | ((d.z & (BIN - 1)) << 18);
        int p3 = atomicAdd(&cur[d.w >> BINSHIFT], 1);
        packed[p3] = s.w | ((d.w & (BIN - 1)) << 18);
    }
    if (blockIdx.x == 0 && t < (E & 3)) {
        int e = (E4 << 2) + t;
        int d = dst[e];
        int p = atomicAdd(&cur[d >> BINSHIFT], 1);
        packed[p] = src[e] | ((d & (BIN - 1)) << 18);
    }
}

// ---- pass D: per-bin counting sort (staged in LDS) + fused mm1 --------------
__global__ void k_binsort(const int* __restrict__ packed,
                          const int* __restrict__ partial, const int* __restrict__ boff,
                          int NBINS, int N, int E,
                          const int* __restrict__ x, const float* __restrict__ emb,
                          const float* __restrict__ W1,
                          int* __restrict__ row_start, float* __restrict__ dinv,
                          int* __restrict__ col, _Float16* __restrict__ sig1) {
    __shared__ int buf[BINCAP];                  // 18 KB staging
    __shared__ int ldeg[BIN];
    __shared__ int lrs[BIN];
    __shared__ int cur[BIN];
    __shared__ float sW[512];                    // W1 (16x32)
    int b = blockIdx.x;
    int t = threadIdx.x;
    int node0 = b << BINSHIFT;
    int e0 = partial[b * NBLK] + boff[b];
    int e1 = (b + 1 < NBINS) ? (partial[(b + 1) * NBLK] + boff[b + 1]) : E;
    int cnt = e1 - e0;
    bool fits = (cnt <= BINCAP);                 // uniform per block
    if (b == 0 && t == 0) row_start[N] = E;      // sentinel
    sW[t] = W1[t];
    sW[t + 256] = W1[t + 256];
    ldeg[t] = 0;
    if (fits)
        for (int i = t; i < cnt; i += BS) buf[i] = packed[e0 + i];
    __syncthreads();
    for (int i = t; i < cnt; i += BS) {
        int v = fits ? buf[i] : packed[e0 + i];
        atomicAdd(&ldeg[((unsigned)v >> 18) & (BIN - 1)], 1);
    }
    __syncthreads();
    lrs[t] = ldeg[t];
    __syncthreads();
    for (int off = 1; off < BIN; off <<= 1) {
        int add = (t >= off) ? lrs[t - off] : 0;
        __syncthreads();
        lrs[t] += add;
        __syncthreads();
    }
    int myDeg = ldeg[t];
    int ex = lrs[t] - myDeg;
    cur[t] = ex;
    int n = node0 + t;                           // one node per thread
    float di = rsqrtf((float)(myDeg + 1));
    if (n < N) {
        row_start[n] = e0 + ex;
        dinv[n] = di;
    }
    __syncthreads();
    for (int i = t; i < cnt; i += BS) {
        int v = fits ? buf[i] : packed[e0 + i];
        int pos = atomicAdd(&cur[((unsigned)v >> 18) & (BIN - 1)], 1);
        col[e0 + pos] = v & 0x3FFFF;
    }
    // ---- fused mm1 for this bin's 256 nodes ----
    if (n < N) {
        const float4* er = (const float4*)(emb + (size_t)x[n] * 16);
        float4 ra = er[0], rb = er[1], rc = er[2], rd = er[3];
        float ev[16] = {ra.x, ra.y, ra.z, ra.w, rb.x, rb.y, rb.z, rb.w,
                        rc.x, rc.y, rc.z, rc.w, rd.x, rd.y, rd.z, rd.w};
        int4* s1o = (int4*)sig1;
        #pragma unroll
        for (int cq = 0; cq < 4; cq++) {
            H2 pk[4];
            #pragma unroll
            for (int dw = 0; dw < 4; dw++) {
                int c = cq * 8 + dw * 2;
                float acc0 = 0.f, acc1 = 0.f;
                #pragma unroll
                for (int k = 0; k < 16; k++) {
                    acc0 += ev[k] * sW[k * 32 + c];
                    acc1 += ev[k] * sW[k * 32 + c + 1];
                }
                pk[dw].h[0] = (_Float16)(acc0 * di);
                pk[dw].h[1] = (_Float16)(acc1 * di);
            }
            int4 pv;
            pv.x = pk[0].i; pv.y = pk[1].i; pv.z = pk[2].i; pv.w = pk[3].i;
            s1o[(size_t)n * 4 + cq] = pv;
        }
    }
}

// ---- fused layer-1 aggregate + b1 + relu + GEMM W2 -> sig2 (fp16) -----------
// 4 NODES per wave: lane = (node g in [0,4)) x (dword-channel cd in [0,16)).
// col prefetched one iteration ahead (overlaps next col load with gathers).
__global__ __launch_bounds__(BS) void k_agg1mm2(
    const _Float16* __restrict__ sig1, const int* __restrict__ row_start,
    const float* __restrict__ dinv, const int* __restrict__ col,
    const float* __restrict__ b1, const float* __restrict__ W2,
    int N, _Float16* __restrict__ sig2) {
    __shared__ float hbuf[4][4][36];   // [wave][node][32 ch + pad]
    int t = threadIdx.x;
    int lane = t & 63;
    int wid = t >> 6;
    int g  = lane >> 4;                // node within wave
    int cd = lane & 15;                // dword channel (2 fp16)
    int n = blockIdx.x * 16 + wid * 4 + g;
    int nld = (n < N) ? n : N - 1;
    int rs = row_start[nld];
    int re = row_start[nld + 1];
    int dn = (n < N) ? (re - rs) : 0;
    int dnm1 = (dn > 0) ? dn - 1 : 0;
    int dm = dn;                       // wave max degree
    dm = max(dm, __shfl_xor(dm, 16));
    dm = max(dm, __shfl_xor(dm, 32));
    float w2c[32];
    #pragma unroll
    for (int k = 0; k < 32; k++) w2c[k] = W2[k * 16 + cd];
    const int* s1i = (const int*)sig1;
    float a0 = 0.f, a1 = 0.f;
    int iters = (dm + 3) >> 2;
    int slot = cd & 3;
    int bidx = lane & 48;              // group base lane
    int colv = 0;
    if (iters > 0) {
        int idx = slot; if (idx > dnm1) idx = dnm1;
        colv = col[rs + idx];
    }
    for (int it = 0; it < iters; it++) {
        int e = it << 2;
        int coln = 0;
        if (it + 1 < iters) {
            int idx = e + 4 + slot; if (idx > dnm1) idx = dnm1;
            coln = col[rs + idx];      // prefetch next round
        }
        int s0 = __shfl(colv, bidx + 0);
        int s1 = __shfl(colv, bidx + 1);
        int s2 = __shfl(colv, bidx + 2);
        int s3 = __shfl(colv, bidx + 3);
        int u0 = s1i[s0 * 16 + cd];    // 4 rows (64B lines) per inst
        int u1 = s1i[s1 * 16 + cd];
        int u2 = s1i[s2 * 16 + cd];
        int u3 = s1i[s3 * 16 + cd];
        u0 = (e + 0 < dn) ? u0 : 0;    // 0x0 == +0.0 fp16 pair
        u1 = (e + 1 < dn) ? u1 : 0;
        u2 = (e + 2 < dn) ? u2 : 0;
        u3 = (e + 3 < dn) ? u3 : 0;
        H2 p0, p1, p2, p3;
        p0.i = u0; p1.i = u1; p2.i = u2; p3.i = u3;
        a0 += ((float)p0.h[0] + (float)p1.h[0]) + ((float)p2.h[0] + (float)p3.h[0]);
        a1 += ((float)p0.h[1] + (float)p1.h[1]) + ((float)p2.h[1] + (float)p3.h[1]);
        colv = coln;
    }
    {   // self-loop (pre-scaled row)
        H2 p; p.i = s1i[nld * 16 + cd];
        a0 += (float)p.h[0];
        a1 += (float)p.h[1];
    }
    float di = dinv[nld];
    float2 b = ((const float2*)b1)[cd];
    float h0 = fmaxf(a0 * di + b.x, 0.f);
    float h1 = fmaxf(a1 * di + b.y, 0.f);
    float* hb = hbuf[wid][g];
    *(float2*)&hb[2 * cd] = make_float2(h0, h1);
    // same-wave LDS produce->consume: in-order ds ops + lgkmcnt, no barrier
    float a = 0.f;
    #pragma unroll
    for (int k = 0; k < 32; k += 4) {
        float4 hv = *(const float4*)&hb[k];
        a = fmaf(hv.x, w2c[k],     a);
        a = fmaf(hv.y, w2c[k + 1], a);
        a = fmaf(hv.z, w2c[k + 2], a);
        a = fmaf(hv.w, w2c[k + 3], a);
    }
    if (n < N) sig2[(size_t)n * 16 + cd] = (_Float16)(a * di);   // pre-scale
}

// ---- layer-2 aggregate + b2 -> out ------------------------------------------
// 4 NODES per wave: lane = (node g) x (edge-half e2) x (dword cd in [0,8)).
__global__ __launch_bounds__(BS) void k_agg2(
    const _Float16* __restrict__ sig2, const int* __restrict__ row_start,
    const float* __restrict__ dinv, const int* __restrict__ col,
    const float* __restrict__ b2, int N, float* __restrict__ out) {
    int t = threadIdx.x;
    int lane = t & 63;
    int g  = lane >> 4;                // node within wave
    int e2 = (lane >> 3) & 1;          // edge half
    int cd = lane & 7;                 // dword channel (2 fp16)
    int n = blockIdx.x * 16 + (t >> 6) * 4 + g;
    int nld = (n < N) ? n : N - 1;
    int rs = row_start[nld];
    int re = row_start[nld + 1];
    int dn = (n < N) ? (re - rs) : 0;
    int dnm1 = (dn > 0) ? dn - 1 : 0;
    int dm = dn;
    dm = max(dm, __shfl_xor(dm, 16));
    dm = max(dm, __shfl_xor(dm, 32));
    const int* s2i = (const int*)sig2;
    float a0 = 0.f, a1 = 0.f;
    int iters = (dm + 7) >> 3;
    int slot = lane & 7;               // this lane's col slot (0..7)
    int bidx = lane & 48;
    int colv = 0;
    if (iters > 0) {
        int idx = slot; if (idx > dnm1) idx = dnm1;
        colv = col[rs + idx];
    }
    for (int it = 0; it < iters; it++) {
        int e = it << 3;
        int coln = 0;
        if (it + 1 < iters) {
            int idx = e + 8 + slot; if (idx > dnm1) idx = dnm1;
            coln = col[rs + idx];      // prefetch next round
        }
        #pragma unroll
        for (int j = 0; j < 4; j++) {
            int sl = 2 * j + e2;
            int sv = __shfl(colv, bidx + sl);
            int u = s2i[sv * 8 + cd];  // 8 rows (32B) per inst
            u = (e + sl < dn) ? u : 0;
            H2 p; p.i = u;
            a0 += (float)p.h[0];
            a1 += (float)p.h[1];
        }
        colv = coln;
    }
    a0 += __shfl_xor(a0, 8);           // combine edge halves
    a1 += __shfl_xor(a1, 8);
    {   // self-loop
        H2 p; p.i = s2i[nld * 8 + cd];
        a0 += (float)p.h[0];
        a1 += (float)p.h[1];
    }
    if (n < N && e2 == 0) {
        float di = dinv[nld];
        float2 b = ((const float2*)b2)[cd];
        float2 o;
        o.x = a0 * di + b.x;
        o.y = a1 * di + b.y;
        ((float2*)out)[(size_t)n * 8 + cd] = o;
    }
}

extern "C" void kernel_launch(void* const* d_in, const int* in_sizes, int n_in,
                              void* d_out, int out_size, void* d_ws, size_t ws_size,
                              hipStream_t stream) {
    const int*   x   = (const int*)d_in[0];
    const int*   ei  = (const int*)d_in[1];
    const float* emb = (const float*)d_in[2];
    const float* W1  = (const float*)d_in[3];
    const float* b1  = (const float*)d_in[4];
    const float* W2  = (const float*)d_in[5];
    const float* b2  = (const float*)d_in[6];
    float* out = (float*)d_out;

    const int N = in_sizes[0];
    const int E = in_sizes[1] / 2;
    const int* srcp = ei;
    const int* dstp = ei + E;
    const int NBINS = (N + BIN - 1) >> BINSHIFT;   // 391 for N=100000
    const int L = NBINS * NBLK;
    const int nB2 = (L + BS - 1) / BS;

    auto al = [](size_t b) { return (b + 255) & ~size_t(255); };
    char* w = (char*)d_ws;
    auto carve = [&](size_t bytes) {
        void* p = (void*)w;
        w += al(bytes);
        return p;
    };
    // no unions: binsort writes sig1 while other blocks still read packed.
    int*   row_start = (int*)carve((size_t)(N + 1) * 4);
    float* dinv      = (float*)carve((size_t)N * 4);
    int*   col       = (int*)carve((size_t)(E + 256) * 4);  // +pad for clamped reads
    int*   histG     = (int*)carve((size_t)L * 4);
    int*   partial   = (int*)carve((size_t)L * 4);
    int*   bsum      = (int*)carve((size_t)nB2 * 4);
    int*   boff      = (int*)carve((size_t)nB2 * 4);
    int*   packed    = (int*)carve((size_t)E * 4);
    _Float16* sig1   = (_Float16*)carve((size_t)N * 32 * 2);
    _Float16* sig2   = (_Float16*)carve((size_t)N * 16 * 2);
    (void)ws_size; (void)n_in; (void)out_size;

    int gL = (L + BS - 1) / BS;
    k_hist<<<NBLK, BSBIG, 0, stream>>>(dstp, E, NBINS, histG);
    k_scanA<<<gL, BS, 0, stream>>>(histG, L, partial, bsum);
    k_scanB<<<1, BS, 0, stream>>>(bsum, nB2, boff);
    k_binscatter<<<NBLK, BSBIG, 0, stream>>>(srcp, dstp, E, NBINS, partial, boff,
                                             packed);
    k_binsort<<<NBINS, BS, 0, stream>>>(packed, partial, boff, NBINS, N, E,
                                        x, emb, W1, row_start, dinv, col, sig1);

    int gA = (N + 15) / 16;            // 4 waves x 4 nodes per block
    k_agg1mm2<<<gA, BS, 0, stream>>>(sig1, row_start, dinv, col, b1, W2, N, sig2);
    k_agg2<<<gA, BS, 0, stream>>>(sig2, row_start, dinv, col, b2, N, out);
}

// Round 18
// 152.593 us; speedup vs baseline: 1.1853x; 1.0250x over previous
//
#include <hip/hip_runtime.h>

// 2-layer GCN: h1 = emb[x] @ W1; agg+b1+relu; @ W2; agg+b2.
// CSR built per-launch via two-level binned counting sort (no global atomics).
// R18 = R14 + deeper edge unroll ONLY (agg1: 8 edges/iter = 8 gathers/lane
// in flight; agg2: 16 edges/iter) -- decomposing R15, which bundled this
// with degree-sort scheduling (the sort's perm indirection + de-coalesced
// writes were on the critical path and regressed; the unroll was never
// measured alone). MLP math: ~144 lines/CU in flight saturate HBM at 900cyc
// latency; R14 had ~96, this has ~190.
// Rejected by measurement: LDS-atomic edge-parallel agg (R3); 16B-per-lane
// gathers (R10); channel-split passes (R7); cooperative fused build (R13);
// degree-sorted scheduling (R15); atomic-counter scan fusion (R16 -- device
// fence flushes per-XCD L2).

#define BS   256
#define BSBIG 1024        // hist/binscatter block size (16 waves)
#define NBLK 256          // blocks for hist/binscatter
#define BINSHIFT 8        // 256 nodes per bin
#define BIN  256
#define MAXBINS 512
#define BINCAP 4608       // LDS packed staging (mean bin = 4092, sigma ~64)

union H2 { int i; _Float16 h[2]; };

// ---- pass A: per-block histograms of dst bins (int4 reads, grid-stride) -----
__global__ __launch_bounds__(BSBIG) void k_hist(
    const int* __restrict__ dst, int E, int NBINS, int* __restrict__ histG) {
    __shared__ int h[MAXBINS];
    int t = threadIdx.x;
    for (int i = t; i < NBINS; i += BSBIG) h[i] = 0;
    __syncthreads();
    int E4 = E >> 2;
    const int4* d4 = (const int4*)dst;
    for (int i = blockIdx.x * BSBIG + t; i < E4; i += NBLK * BSBIG) {
        int4 d = d4[i];
        atomicAdd(&h[d.x >> BINSHIFT], 1);
        atomicAdd(&h[d.y >> BINSHIFT], 1);
        atomicAdd(&h[d.z >> BINSHIFT], 1);
        atomicAdd(&h[d.w >> BINSHIFT], 1);
    }
    if (blockIdx.x == 0 && t < (E & 3))
        atomicAdd(&h[dst[(E4 << 2) + t] >> BINSHIFT], 1);
    __syncthreads();
    for (int i = t; i < NBINS; i += BSBIG) histG[i * NBLK + blockIdx.x] = h[i];
}

// ---- hierarchical exclusive scan over L = NBINS*NBLK ints -------------------
__global__ void k_scanA(const int* __restrict__ in, int L,
                        int* __restrict__ partial, int* __restrict__ bsum) {
    __shared__ int s[BS];
    int t = threadIdx.x;
    int i = blockIdx.x * BS + t;
    int v = (i < L) ? in[i] : 0;
    s[t] = v;
    __syncthreads();
    for (int off = 1; off < BS; off <<= 1) {
        int add = (t >= off) ? s[t - off] : 0;
        __syncthreads();
        s[t] += add;
        __syncthreads();
    }
    if (i < L) partial[i] = s[t] - v;
    if (t == BS - 1) bsum[blockIdx.x] = s[BS - 1];
}

__global__ void k_scanB(const int* __restrict__ bsum, int nB, int* __restrict__ boff) {
    __shared__ int s[BS];
    int t = threadIdx.x;
    int PER = (nB + BS - 1) / BS;
    int loc[8];
    int base = t * PER;
    int sum = 0;
    for (int j = 0; j < PER && j < 8; j++) {
        int idx = base + j;
        int v = (idx < nB) ? bsum[idx] : 0;
        loc[j] = sum;
        sum += v;
    }
    s[t] = sum;
    __syncthreads();
    for (int off = 1; off < BS; off <<= 1) {
        int add = (t >= off) ? s[t - off] : 0;
        __syncthreads();
        s[t] += add;
        __syncthreads();
    }
    int ex = s[t] - sum;
    for (int j = 0; j < PER && j < 8; j++) {
        int idx = base + j;
        if (idx < nB) boff[idx] = ex + loc[j];
    }
}

// ---- pass C: scatter edges into bin-partitioned order (LDS cursors only) ----
// ONE packed 4B write per edge: src | dstLocal<<18  (src < 2^18).
__global__ __launch_bounds__(BSBIG) void k_binscatter(
    const int* __restrict__ src, const int* __restrict__ dst,
    int E, int NBINS, const int* __restrict__ partial,
    const int* __restrict__ boff, int* __restrict__ packed) {
    __shared__ int cur[MAXBINS];
    int t = threadIdx.x;
    for (int i = t; i < NBINS; i += BSBIG)
        cur[i] = partial[i * NBLK + blockIdx.x] + boff[i];
    __syncthreads();
    int E4 = E >> 2;
    const int4* s4 = (const int4*)src;
    const int4* d4 = (const int4*)dst;
    for (int i = blockIdx.x * BSBIG + t; i < E4; i += NBLK * BSBIG) {
        int4 s = s4[i];
        int4 d = d4[i];
        int p0 = atomicAdd(&cur[d.x >> BINSHIFT], 1);
        packed[p0] = s.x | ((d.x & (BIN - 1)) << 18);
        int p1 = atomicAdd(&cur[d.y >> BINSHIFT], 1);
        packed[p1] = s.y | ((d.y & (BIN - 1)) << 18);
        int p2 = atomicAdd(&cur[d.z >> BINSHIFT], 1);
        packed[p2] = s.z | ((d.z & (BIN - 1)) << 18);
        int p3 = atomicAdd(&cur[d.w >> BINSHIFT], 1);
        packed[p3] = s.w | ((d.w & (BIN - 1)) << 18);
    }
    if (blockIdx.x == 0 && t < (E & 3)) {
        int e = (E4 << 2) + t;
        int d = dst[e];
        int p = atomicAdd(&cur[d >> BINSHIFT], 1);
        packed[p] = src[e] | ((d & (BIN - 1)) << 18);
    }
}

// ---- pass D: per-bin counting sort (staged in LDS) + fused mm1 --------------
__global__ void k_binsort(const int* __restrict__ packed,
                          const int* __restrict__ partial, const int* __restrict__ boff,
                          int NBINS, int N, int E,
                          const int* __restrict__ x, const float* __restrict__ emb,
                          const float* __restrict__ W1,
                          int* __restrict__ row_start, float* __restrict__ dinv,
                          int* __restrict__ col, _Float16* __restrict__ sig1) {
    __shared__ int buf[BINCAP];                  // 18 KB staging
    __shared__ int ldeg[BIN];
    __shared__ int lrs[BIN];
    __shared__ int cur[BIN];
    __shared__ float sW[512];                    // W1 (16x32)
    int b = blockIdx.x;
    int t = threadIdx.x;
    int node0 = b << BINSHIFT;
    int e0 = partial[b * NBLK] + boff[b];
    int e1 = (b + 1 < NBINS) ? (partial[(b + 1) * NBLK] + boff[b + 1]) : E;
    int cnt = e1 - e0;
    bool fits = (cnt <= BINCAP);                 // uniform per block
    if (b == 0 && t == 0) row_start[N] = E;      // sentinel
    sW[t] = W1[t];
    sW[t + 256] = W1[t + 256];
    ldeg[t] = 0;
    if (fits)
        for (int i = t; i < cnt; i += BS) buf[i] = packed[e0 + i];
    __syncthreads();
    for (int i = t; i < cnt; i += BS) {
        int v = fits ? buf[i] : packed[e0 + i];
        atomicAdd(&ldeg[((unsigned)v >> 18) & (BIN - 1)], 1);
    }
    __syncthreads();
    lrs[t] = ldeg[t];
    __syncthreads();
    for (int off = 1; off < BIN; off <<= 1) {
        int add = (t >= off) ? lrs[t - off] : 0;
        __syncthreads();
        lrs[t] += add;
        __syncthreads();
    }
    int myDeg = ldeg[t];
    int ex = lrs[t] - myDeg;
    cur[t] = ex;
    int n = node0 + t;                           // one node per thread
    float di = rsqrtf((float)(myDeg + 1));
    if (n < N) {
        row_start[n] = e0 + ex;
        dinv[n] = di;
    }
    __syncthreads();
    for (int i = t; i < cnt; i += BS) {
        int v = fits ? buf[i] : packed[e0 + i];
        int pos = atomicAdd(&cur[((unsigned)v >> 18) & (BIN - 1)], 1);
        col[e0 + pos] = v & 0x3FFFF;
    }
    // ---- fused mm1 for this bin's 256 nodes ----
    if (n < N) {
        const float4* er = (const float4*)(emb + (size_t)x[n] * 16);
        float4 ra = er[0], rb = er[1], rc = er[2], rd = er[3];
        float ev[16] = {ra.x, ra.y, ra.z, ra.w, rb.x, rb.y, rb.z, rb.w,
                        rc.x, rc.y, rc.z, rc.w, rd.x, rd.y, rd.z, rd.w};
        int4* s1o = (int4*)sig1;
        #pragma unroll
        for (int cq = 0; cq < 4; cq++) {
            H2 pk[4];
            #pragma unroll
            for (int dw = 0; dw < 4; dw++) {
                int c = cq * 8 + dw * 2;
                float acc0 = 0.f, acc1 = 0.f;
                #pragma unroll
                for (int k = 0; k < 16; k++) {
                    acc0 += ev[k] * sW[k * 32 + c];
                    acc1 += ev[k] * sW[k * 32 + c + 1];
                }
                pk[dw].h[0] = (_Float16)(acc0 * di);
                pk[dw].h[1] = (_Float16)(acc1 * di);
            }
            int4 pv;
            pv.x = pk[0].i; pv.y = pk[1].i; pv.z = pk[2].i; pv.w = pk[3].i;
            s1o[(size_t)n * 4 + cq] = pv;
        }
    }
}

// ---- fused layer-1 aggregate + b1 + relu + GEMM W2 -> sig2 (fp16) -----------
// 4 NODES per wave: lane = (node g in [0,4)) x (dword-channel cd in [0,16)).
// 8 edges/iter: 8 gathers in flight per lane; col prefetched one iter ahead.
__global__ __launch_bounds__(BS) void k_agg1mm2(
    const _Float16* __restrict__ sig1, const int* __restrict__ row_start,
    const float* __restrict__ dinv, const int* __restrict__ col,
    const float* __restrict__ b1, const float* __restrict__ W2,
    int N, _Float16* __restrict__ sig2) {
    __shared__ float hbuf[4][4][36];   // [wave][node][32 ch + pad]
    int t = threadIdx.x;
    int lane = t & 63;
    int wid = t >> 6;
    int g  = lane >> 4;                // node within wave
    int cd = lane & 15;                // dword channel (2 fp16)
    int n = blockIdx.x * 16 + wid * 4 + g;
    int nld = (n < N) ? n : N - 1;
    int rs = row_start[nld];
    int re = row_start[nld + 1];
    int dn = (n < N) ? (re - rs) : 0;
    int dnm1 = (dn > 0) ? dn - 1 : 0;
    int dm = dn;                       // wave max degree
    dm = max(dm, __shfl_xor(dm, 16));
    dm = max(dm, __shfl_xor(dm, 32));
    float w2c[32];
    #pragma unroll
    for (int k = 0; k < 32; k++) w2c[k] = W2[k * 16 + cd];
    const int* s1i = (const int*)sig1;
    float a0 = 0.f, a1 = 0.f;
    int iters = (dm + 7) >> 3;
    int slot = cd & 7;
    int bidx = lane & 48;              // group base lane
    int colv = 0;
    if (iters > 0) {
        int idx = slot; if (idx > dnm1) idx = dnm1;
        colv = col[rs + idx];
    }
    for (int it = 0; it < iters; it++) {
        int e = it << 3;
        int coln = 0;
        if (it + 1 < iters) {
            int idx = e + 8 + slot; if (idx > dnm1) idx = dnm1;
            coln = col[rs + idx];      // prefetch next round
        }
        int s0 = __shfl(colv, bidx + 0);
        int s1 = __shfl(colv, bidx + 1);
        int s2 = __shfl(colv, bidx + 2);
        int s3 = __shfl(colv, bidx + 3);
        int s4 = __shfl(colv, bidx + 4);
        int s5 = __shfl(colv, bidx + 5);
        int s6 = __shfl(colv, bidx + 6);
        int s7 = __shfl(colv, bidx + 7);
        int u0 = s1i[s0 * 16 + cd];    // 8 rows (64B lines) in flight
        int u1 = s1i[s1 * 16 + cd];
        int u2 = s1i[s2 * 16 + cd];
        int u3 = s1i[s3 * 16 + cd];
        int u4 = s1i[s4 * 16 + cd];
        int u5 = s1i[s5 * 16 + cd];
        int u6 = s1i[s6 * 16 + cd];
        int u7 = s1i[s7 * 16 + cd];
        u0 = (e + 0 < dn) ? u0 : 0;    // 0x0 == +0.0 fp16 pair
        u1 = (e + 1 < dn) ? u1 : 0;
        u2 = (e + 2 < dn) ? u2 : 0;
        u3 = (e + 3 < dn) ? u3 : 0;
        u4 = (e + 4 < dn) ? u4 : 0;
        u5 = (e + 5 < dn) ? u5 : 0;
        u6 = (e + 6 < dn) ? u6 : 0;
        u7 = (e + 7 < dn) ? u7 : 0;
        H2 p0, p1, p2, p3;
        p0.i = u0; p1.i = u1; p2.i = u2; p3.i = u3;
        a0 += ((float)p0.h[0] + (float)p1.h[0]) + ((float)p2.h[0] + (float)p3.h[0]);
        a1 += ((float)p0.h[1] + (float)p1.h[1]) + ((float)p2.h[1] + (float)p3.h[1]);
        p0.i = u4; p1.i = u5; p2.i = u6; p3.i = u7;
        a0 += ((float)p0.h[0] + (float)p1.h[0]) + ((float)p2.h[0] + (float)p3.h[0]);
        a1 += ((float)p0.h[1] + (float)p1.h[1]) + ((float)p2.h[1] + (float)p3.h[1]);
        colv = coln;
    }
    {   // self-loop (pre-scaled row)
        H2 p; p.i = s1i[nld * 16 + cd];
        a0 += (float)p.h[0];
        a1 += (float)p.h[1];
    }
    float di = dinv[nld];
    float2 b = ((const float2*)b1)[cd];
    float h0 = fmaxf(a0 * di + b.x, 0.f);
    float h1 = fmaxf(a1 * di + b.y, 0.f);
    float* hb = hbuf[wid][g];
    *(float2*)&hb[2 * cd] = make_float2(h0, h1);
    // same-wave LDS produce->consume: in-order ds ops + lgkmcnt, no barrier
    float a = 0.f;
    #pragma unroll
    for (int k = 0; k < 32; k += 4) {
        float4 hv = *(const float4*)&hb[k];
        a = fmaf(hv.x, w2c[k],     a);
        a = fmaf(hv.y, w2c[k + 1], a);
        a = fmaf(hv.z, w2c[k + 2], a);
        a = fmaf(hv.w, w2c[k + 3], a);
    }
    if (n < N) sig2[(size_t)n * 16 + cd] = (_Float16)(a * di);   // pre-scale
}

// ---- layer-2 aggregate + b2 -> out ------------------------------------------
// 4 NODES per wave: lane = (node g) x (edge-half e2) x (dword cd in [0,8)).
// 16 edges/iter: 8 gathers (8 rows each) in flight; col prefetch.
__global__ __launch_bounds__(BS) void k_agg2(
    const _Float16* __restrict__ sig2, const int* __restrict__ row_start,
    const float* __restrict__ dinv, const int* __restrict__ col,
    const float* __restrict__ b2, int N, float* __restrict__ out) {
    int t = threadIdx.x;
    int lane = t & 63;
    int g  = lane >> 4;                // node within wave
    int e2 = (lane >> 3) & 1;          // edge half
    int cd = lane & 7;                 // dword channel (2 fp16)
    int n = blockIdx.x * 16 + (t >> 6) * 4 + g;
    int nld = (n < N) ? n : N - 1;
    int rs = row_start[nld];
    int re = row_start[nld + 1];
    int dn = (n < N) ? (re - rs) : 0;
    int dnm1 = (dn > 0) ? dn - 1 : 0;
    int dm = dn;
    dm = max(dm, __shfl_xor(dm, 16));
    dm = max(dm, __shfl_xor(dm, 32));
    const int* s2i = (const int*)sig2;
    float a0 = 0.f, a1 = 0.f;
    int iters = (dm + 15) >> 4;
    int slot = lane & 15;              // this lane's col slot (0..15)
    int bidx = lane & 48;
    int colv = 0;
    if (iters > 0) {
        int idx = slot; if (idx > dnm1) idx = dnm1;
        colv = col[rs + idx];
    }
    for (int it = 0; it < iters; it++) {
        int e = it << 4;
        int coln = 0;
        if (it + 1 < iters) {
            int idx = e + 16 + slot; if (idx > dnm1) idx = dnm1;
            coln = col[rs + idx];      // prefetch next round
        }
        #pragma unroll
        for (int j = 0; j < 8; j++) {
            int sl = 2 * j + e2;
            int sv = __shfl(colv, bidx + sl);
            int u = s2i[sv * 8 + cd];  // 8 rows (32B) per inst
            u = (e + sl < dn) ? u : 0;
            H2 p; p.i = u;
            a0 += (float)p.h[0];
            a1 += (float)p.h[1];
        }
        colv = coln;
    }
    a0 += __shfl_xor(a0, 8);           // combine edge halves
    a1 += __shfl_xor(a1, 8);
    {   // self-loop
        H2 p; p.i = s2i[nld * 8 + cd];
        a0 += (float)p.h[0];
        a1 += (float)p.h[1];
    }
    if (n < N && e2 == 0) {
        float di = dinv[nld];
        float2 b = ((const float2*)b2)[cd];
        float2 o;
        o.x = a0 * di + b.x;
        o.y = a1 * di + b.y;
        ((float2*)out)[(size_t)n * 8 + cd] = o;
    }
}

extern "C" void kernel_launch(void* const* d_in, const int* in_sizes, int n_in,
                              void* d_out, int out_size, void* d_ws, size_t ws_size,
                              hipStream_t stream) {
    const int*   x   = (const int*)d_in[0];
    const int*   ei  = (const int*)d_in[1];
    const float* emb = (const float*)d_in[2];
    const float* W1  = (const float*)d_in[3];
    const float* b1  = (const float*)d_in[4];
    const float* W2  = (const float*)d_in[5];
    const float* b2  = (const float*)d_in[6];
    float* out = (float*)d_out;

    const int N = in_sizes[0];
    const int E = in_sizes[1] / 2;
    const int* srcp = ei;
    const int* dstp = ei + E;
    const int NBINS = (N + BIN - 1) >> BINSHIFT;   // 391 for N=100000
    const int L = NBINS * NBLK;
    const int nB2 = (L + BS - 1) / BS;

    auto al = [](size_t b) { return (b + 255) & ~size_t(255); };
    char* w = (char*)d_ws;
    auto carve = [&](size_t bytes) {
        void* p = (void*)w;
        w += al(bytes);
        return p;
    };
    // no unions: binsort writes sig1 while other blocks still read packed.
    int*   row_start = (int*)carve((size_t)(N + 1) * 4);
    float* dinv      = (float*)carve((size_t)N * 4);
    int*   col       = (int*)carve((size_t)(E + 256) * 4);  // +pad for clamped reads
    int*   histG     = (int*)carve((size_t)L * 4);
    int*   partial   = (int*)carve((size_t)L * 4);
    int*   bsum      = (int*)carve((size_t)nB2 * 4);
    int*   boff      = (int*)carve((size_t)nB2 * 4);
    int*   packed    = (int*)carve((size_t)E * 4);
    _Float16* sig1   = (_Float16*)carve((size_t)N * 32 * 2);
    _Float16* sig2   = (_Float16*)carve((size_t)N * 16 * 2);
    (void)ws_size; (void)n_in; (void)out_size;

    int gL = (L + BS - 1) / BS;
    k_hist<<<NBLK, BSBIG, 0, stream>>>(dstp, E, NBINS, histG);
    k_scanA<<<gL, BS, 0, stream>>>(histG, L, partial, bsum);
    k_scanB<<<1, BS, 0, stream>>>(bsum, nB2, boff);
    k_binscatter<<<NBLK, BSBIG, 0, stream>>>(srcp, dstp, E, NBINS, partial, boff,
                                             packed);
    k_binsort<<<NBINS, BS, 0, stream>>>(packed, partial, boff, NBINS, N, E,
                                        x, emb, W1, row_start, dinv, col, sig1);

    int gA = (N + 15) / 16;            // 4 waves x 4 nodes per block
    k_agg1mm2<<<gA, BS, 0, stream>>>(sig1, row_start, dinv, col, b1, W2, N, sig2);
    k_agg2<<<gA, BS, 0, stream>>>(sig2, row_start, dinv, col, b2, N, out);
}

// Round 19
// 151.698 us; speedup vs baseline: 1.1923x; 1.0059x over previous
//
#include <hip/hip_runtime.h>

// 2-layer GCN: h1 = emb[x] @ W1; agg+b1+relu; @ W2; agg+b2.
// CSR built per-launch via two-level binned counting sort (no global atomics).
// R19 = R18 + scanB eliminated by redundant recompute: each binscatter
// block scans the 391 block-sums in LDS itself (bsum is 1.5KB L2-hot;
// ~1us overlapped) and block 0 publishes boff for binsort. No fence, no
// occupancy change -- unlike R16's atomic-counter fusion (device fence
// flushed per-XCD L2, +25us).
// Rejected by measurement: LDS-atomic edge-parallel agg (R3); 16B-per-lane
// gathers (R10); channel-split passes (R7); cooperative fused build (R13);
// degree-sorted scheduling (R15); atomic-counter scan fusion (R16).

#define BS   256
#define BSBIG 1024        // hist/binscatter block size (16 waves)
#define NBLK 256          // blocks for hist/binscatter
#define BINSHIFT 8        // 256 nodes per bin
#define BIN  256
#define MAXBINS 512
#define BINCAP 4608       // LDS packed staging (mean bin = 4092, sigma ~64)

union H2 { int i; _Float16 h[2]; };

// ---- pass A: per-block histograms of dst bins (int4 reads, grid-stride) -----
__global__ __launch_bounds__(BSBIG) void k_hist(
    const int* __restrict__ dst, int E, int NBINS, int* __restrict__ histG) {
    __shared__ int h[MAXBINS];
    int t = threadIdx.x;
    for (int i = t; i < NBINS; i += BSBIG) h[i] = 0;
    __syncthreads();
    int E4 = E >> 2;
    const int4* d4 = (const int4*)dst;
    for (int i = blockIdx.x * BSBIG + t; i < E4; i += NBLK * BSBIG) {
        int4 d = d4[i];
        atomicAdd(&h[d.x >> BINSHIFT], 1);
        atomicAdd(&h[d.y >> BINSHIFT], 1);
        atomicAdd(&h[d.z >> BINSHIFT], 1);
        atomicAdd(&h[d.w >> BINSHIFT], 1);
    }
    if (blockIdx.x == 0 && t < (E & 3))
        atomicAdd(&h[dst[(E4 << 2) + t] >> BINSHIFT], 1);
    __syncthreads();
    for (int i = t; i < NBINS; i += BSBIG) histG[i * NBLK + blockIdx.x] = h[i];
}

// ---- hierarchical exclusive scan over L = NBINS*NBLK ints -------------------
__global__ void k_scanA(const int* __restrict__ in, int L,
                        int* __restrict__ partial, int* __restrict__ bsum) {
    __shared__ int s[BS];
    int t = threadIdx.x;
    int i = blockIdx.x * BS + t;
    int v = (i < L) ? in[i] : 0;
    s[t] = v;
    __syncthreads();
    for (int off = 1; off < BS; off <<= 1) {
        int add = (t >= off) ? s[t - off] : 0;
        __syncthreads();
        s[t] += add;
        __syncthreads();
    }
    if (i < L) partial[i] = s[t] - v;
    if (t == BS - 1) bsum[blockIdx.x] = s[BS - 1];
}

// ---- pass C: scatter edges into bin-partitioned order (LDS cursors only) ----
// ONE packed 4B write per edge: src | dstLocal<<18  (src < 2^18).
// scanB folded in: every block scans bsum[0..nB) in LDS (redundant, ~1us,
// L2-broadcast); block 0 publishes boff to global for k_binsort.
__global__ __launch_bounds__(BSBIG) void k_binscatter(
    const int* __restrict__ src, const int* __restrict__ dst,
    int E, int NBINS, int nB, const int* __restrict__ partial,
    const int* __restrict__ bsum, int* __restrict__ boff,
    int* __restrict__ packed) {
    __shared__ int cur[MAXBINS];
    __shared__ int bofl[MAXBINS];
    __shared__ int ssc[BS];
    int t = threadIdx.x;
    // exclusive scan of bsum (nB <= 512) using threads 0..255
    int PERs = (nB + BS - 1) / BS;               // <= 2
    int loc[4];
    int sbase = t * PERs;
    int ssum = 0;
    if (t < BS) {
        for (int j = 0; j < PERs && j < 4; j++) {
            int idx = sbase + j;
            int v = (idx < nB) ? bsum[idx] : 0;
            loc[j] = ssum;
            ssum += v;
        }
        ssc[t] = ssum;
    }
    __syncthreads();
    for (int off = 1; off < BS; off <<= 1) {
        int add = (t < BS && t >= off) ? ssc[t - off] : 0;
        __syncthreads();
        if (t < BS) ssc[t] += add;
        __syncthreads();
    }
    if (t < BS) {
        int ex = ssc[t] - ssum;
        for (int j = 0; j < PERs && j < 4; j++) {
            int idx = sbase + j;
            if (idx < nB) bofl[idx] = ex + loc[j];
        }
    }
    __syncthreads();
    for (int i = t; i < NBINS; i += BSBIG)
        cur[i] = partial[i * NBLK + blockIdx.x] + bofl[i];
    if (blockIdx.x == 0)
        for (int i = t; i < nB; i += BSBIG) boff[i] = bofl[i];
    __syncthreads();
    int E4 = E >> 2;
    const int4* s4 = (const int4*)src;
    const int4* d4 = (const int4*)dst;
    for (int i = blockIdx.x * BSBIG + t; i < E4; i += NBLK * BSBIG) {
        int4 s = s4[i];
        int4 d = d4[i];
        int p0 = atomicAdd(&cur[d.x >> BINSHIFT], 1);
        packed[p0] = s.x | ((d.x & (BIN - 1)) << 18);
        int p1 = atomicAdd(&cur[d.y >> BINSHIFT], 1);
        packed[p1] = s.y | ((d.y & (BIN - 1)) << 18);
        int p2 = atomicAdd(&cur[d.z >> BINSHIFT], 1);
        packed[p2] = s.z | ((d.z & (BIN - 1)) << 18);
        int p3 = atomicAdd(&cur[d.w >> BINSHIFT], 1);
        packed[p3] = s.w | ((d.w & (BIN - 1)) << 18);
    }
    if (blockIdx.x == 0 && t < (E & 3)) {
        int e = (E4 << 2) + t;
        int d = dst[e];
        int p = atomicAdd(&cur[d >> BINSHIFT], 1);
        packed[p] = src[e] | ((d & (BIN - 1)) << 18);
    }
}

// ---- pass D: per-bin counting sort (staged in LDS) + fused mm1 --------------
__global__ void k_binsort(const int* __restrict__ packed,
                          const int* __restrict__ partial, const int* __restrict__ boff,
                          int NBINS, int N, int E,
                          const int* __restrict__ x, const float* __restrict__ emb,
                          const float* __restrict__ W1,
                          int* __restrict__ row_start, float* __restrict__ dinv,
                          int* __restrict__ col, _Float16* __restrict__ sig1) {
    __shared__ int buf[BINCAP];                  // 18 KB staging
    __shared__ int ldeg[BIN];
    __shared__ int lrs[BIN];
    __shared__ int cur[BIN];
    __shared__ float sW[512];                    // W1 (16x32)
    int b = blockIdx.x;
    int t = threadIdx.x;
    int node0 = b << BINSHIFT;
    int e0 = partial[b * NBLK] + boff[b];
    int e1 = (b + 1 < NBINS) ? (partial[(b + 1) * NBLK] + boff[b + 1]) : E;
    int cnt = e1 - e0;
    bool fits = (cnt <= BINCAP);                 // uniform per block
    if (b == 0 && t == 0) row_start[N] = E;      // sentinel
    sW[t] = W1[t];
    sW[t + 256] = W1[t + 256];
    ldeg[t] = 0;
    if (fits)
        for (int i = t; i < cnt; i += BS) buf[i] = packed[e0 + i];
    __syncthreads();
    for (int i = t; i < cnt; i += BS) {
        int v = fits ? buf[i] : packed[e0 + i];
        atomicAdd(&ldeg[((unsigned)v >> 18) & (BIN - 1)], 1);
    }
    __syncthreads();
    lrs[t] = ldeg[t];
    __syncthreads();
    for (int off = 1; off < BIN; off <<= 1) {
        int add = (t >= off) ? lrs[t - off] : 0;
        __syncthreads();
        lrs[t] += add;
        __syncthreads();
    }
    int myDeg = ldeg[t];
    int ex = lrs[t] - myDeg;
    cur[t] = ex;
    int n = node0 + t;                           // one node per thread
    float di = rsqrtf((float)(myDeg + 1));
    if (n < N) {
        row_start[n] = e0 + ex;
        dinv[n] = di;
    }
    __syncthreads();
    for (int i = t; i < cnt; i += BS) {
        int v = fits ? buf[i] : packed[e0 + i];
        int pos = atomicAdd(&cur[((unsigned)v >> 18) & (BIN - 1)], 1);
        col[e0 + pos] = v & 0x3FFFF;
    }
    // ---- fused mm1 for this bin's 256 nodes ----
    if (n < N) {
        const float4* er = (const float4*)(emb + (size_t)x[n] * 16);
        float4 ra = er[0], rb = er[1], rc = er[2], rd = er[3];
        float ev[16] = {ra.x, ra.y, ra.z, ra.w, rb.x, rb.y, rb.z, rb.w,
                        rc.x, rc.y, rc.z, rc.w, rd.x, rd.y, rd.z, rd.w};
        int4* s1o = (int4*)sig1;
        #pragma unroll
        for (int cq = 0; cq < 4; cq++) {
            H2 pk[4];
            #pragma unroll
            for (int dw = 0; dw < 4; dw++) {
                int c = cq * 8 + dw * 2;
                float acc0 = 0.f, acc1 = 0.f;
                #pragma unroll
                for (int k = 0; k < 16; k++) {
                    acc0 += ev[k] * sW[k * 32 + c];
                    acc1 += ev[k] * sW[k * 32 + c + 1];
                }
                pk[dw].h[0] = (_Float16)(acc0 * di);
                pk[dw].h[1] = (_Float16)(acc1 * di);
            }
            int4 pv;
            pv.x = pk[0].i; pv.y = pk[1].i; pv.z = pk[2].i; pv.w = pk[3].i;
            s1o[(size_t)n * 4 + cq] = pv;
        }
    }
}

// ---- fused layer-1 aggregate + b1 + relu + GEMM W2 -> sig2 (fp16) -----------
// 4 NODES per wave: lane = (node g in [0,4)) x (dword-channel cd in [0,16)).
// 8 edges/iter: 8 gathers in flight per lane; col prefetched one iter ahead.
__global__ __launch_bounds__(BS) void k_agg1mm2(
    const _Float16* __restrict__ sig1, const int* __restrict__ row_start,
    const float* __restrict__ dinv, const int* __restrict__ col,
    const float* __restrict__ b1, const float* __restrict__ W2,
    int N, _Float16* __restrict__ sig2) {
    __shared__ float hbuf[4][4][36];   // [wave][node][32 ch + pad]
    int t = threadIdx.x;
    int lane = t & 63;
    int wid = t >> 6;
    int g  = lane >> 4;                // node within wave
    int cd = lane & 15;                // dword channel (2 fp16)
    int n = blockIdx.x * 16 + wid * 4 + g;
    int nld = (n < N) ? n : N - 1;
    int rs = row_start[nld];
    int re = row_start[nld + 1];
    int dn = (n < N) ? (re - rs) : 0;
    int dnm1 = (dn > 0) ? dn - 1 : 0;
    int dm = dn;                       // wave max degree
    dm = max(dm, __shfl_xor(dm, 16));
    dm = max(dm, __shfl_xor(dm, 32));
    float w2c[32];
    #pragma unroll
    for (int k = 0; k < 32; k++) w2c[k] = W2[k * 16 + cd];
    const int* s1i = (const int*)sig1;
    float a0 = 0.f, a1 = 0.f;
    int iters = (dm + 7) >> 3;
    int slot = cd & 7;
    int bidx = lane & 48;              // group base lane
    int colv = 0;
    if (iters > 0) {
        int idx = slot; if (idx > dnm1) idx = dnm1;
        colv = col[rs + idx];
    }
    for (int it = 0; it < iters; it++) {
        int e = it << 3;
        int coln = 0;
        if (it + 1 < iters) {
            int idx = e + 8 + slot; if (idx > dnm1) idx = dnm1;
            coln = col[rs + idx];      // prefetch next round
        }
        int s0 = __shfl(colv, bidx + 0);
        int s1 = __shfl(colv, bidx + 1);
        int s2 = __shfl(colv, bidx + 2);
        int s3 = __shfl(colv, bidx + 3);
        int s4 = __shfl(colv, bidx + 4);
        int s5 = __shfl(colv, bidx + 5);
        int s6 = __shfl(colv, bidx + 6);
        int s7 = __shfl(colv, bidx + 7);
        int u0 = s1i[s0 * 16 + cd];    // 8 rows (64B lines) in flight
        int u1 = s1i[s1 * 16 + cd];
        int u2 = s1i[s2 * 16 + cd];
        int u3 = s1i[s3 * 16 + cd];
        int u4 = s1i[s4 * 16 + cd];
        int u5 = s1i[s5 * 16 + cd];
        int u6 = s1i[s6 * 16 + cd];
        int u7 = s1i[s7 * 16 + cd];
        u0 = (e + 0 < dn) ? u0 : 0;    // 0x0 == +0.0 fp16 pair
        u1 = (e + 1 < dn) ? u1 : 0;
        u2 = (e + 2 < dn) ? u2 : 0;
        u3 = (e + 3 < dn) ? u3 : 0;
        u4 = (e + 4 < dn) ? u4 : 0;
        u5 = (e + 5 < dn) ? u5 : 0;
        u6 = (e + 6 < dn) ? u6 : 0;
        u7 = (e + 7 < dn) ? u7 : 0;
        H2 p0, p1, p2, p3;
        p0.i = u0; p1.i = u1; p2.i = u2; p3.i = u3;
        a0 += ((float)p0.h[0] + (float)p1.h[0]) + ((float)p2.h[0] + (float)p3.h[0]);
        a1 += ((float)p0.h[1] + (float)p1.h[1]) + ((float)p2.h[1] + (float)p3.h[1]);
        p0.i = u4; p1.i = u5; p2.i = u6; p3.i = u7;
        a0 += ((float)p0.h[0] + (float)p1.h[0]) + ((float)p2.h[0] + (float)p3.h[0]);
        a1 += ((float)p0.h[1] + (float)p1.h[1]) + ((float)p2.h[1] + (float)p3.h[1]);
        colv = coln;
    }
    {   // self-loop (pre-scaled row)
        H2 p; p.i = s1i[nld * 16 + cd];
        a0 += (float)p.h[0];
        a1 += (float)p.h[1];
    }
    float di = dinv[nld];
    float2 b = ((const float2*)b1)[cd];
    float h0 = fmaxf(a0 * di + b.x, 0.f);
    float h1 = fmaxf(a1 * di + b.y, 0.f);
    float* hb = hbuf[wid][g];
    *(float2*)&hb[2 * cd] = make_float2(h0, h1);
    // same-wave LDS produce->consume: in-order ds ops + lgkmcnt, no barrier
    float a = 0.f;
    #pragma unroll
    for (int k = 0; k < 32; k += 4) {
        float4 hv = *(const float4*)&hb[k];
        a = fmaf(hv.x, w2c[k],     a);
        a = fmaf(hv.y, w2c[k + 1], a);
        a = fmaf(hv.z, w2c[k + 2], a);
        a = fmaf(hv.w, w2c[k + 3], a);
    }
    if (n < N) sig2[(size_t)n * 16 + cd] = (_Float16)(a * di);   // pre-scale
}

// ---- layer-2 aggregate + b2 -> out ------------------------------------------
// 4 NODES per wave: lane = (node g) x (edge-half e2) x (dword cd in [0,8)).
// 16 edges/iter: 8 gathers (8 rows each) in flight; col prefetch.
__global__ __launch_bounds__(BS) void k_agg2(
    const _Float16* __restrict__ sig2, const int* __restrict__ row_start,
    const float* __restrict__ dinv, const int* __restrict__ col,
    const float* __restrict__ b2, int N, float* __restrict__ out) {
    int t = threadIdx.x;
    int lane = t & 63;
    int g  = lane >> 4;                // node within wave
    int e2 = (lane >> 3) & 1;          // edge half
    int cd = lane & 7;                 // dword channel (2 fp16)
    int n = blockIdx.x * 16 + (t >> 6) * 4 + g;
    int nld = (n < N) ? n : N - 1;
    int rs = row_start[nld];
    int re = row_start[nld + 1];
    int dn = (n < N) ? (re - rs) : 0;
    int dnm1 = (dn > 0) ? dn - 1 : 0;
    int dm = dn;
    dm = max(dm, __shfl_xor(dm, 16));
    dm = max(dm, __shfl_xor(dm, 32));
    const int* s2i = (const int*)sig2;
    float a0 = 0.f, a1 = 0.f;
    int iters = (dm + 15) >> 4;
    int slot = lane & 15;              // this lane's col slot (0..15)
    int bidx = lane & 48;
    int colv = 0;
    if (iters > 0) {
        int idx = slot; if (idx > dnm1) idx = dnm1;
        colv = col[rs + idx];
    }
    for (int it = 0; it < iters; it++) {
        int e = it << 4;
        int coln = 0;
        if (it + 1 < iters) {
            int idx = e + 16 + slot; if (idx > dnm1) idx = dnm1;
            coln = col[rs + idx];      // prefetch next round
        }
        #pragma unroll
        for (int j = 0; j < 8; j++) {
            int sl = 2 * j + e2;
            int sv = __shfl(colv, bidx + sl);
            int u = s2i[sv * 8 + cd];  // 8 rows (32B) per inst
            u = (e + sl < dn) ? u : 0;
            H2 p; p.i = u;
            a0 += (float)p.h[0];
            a1 += (float)p.h[1];
        }
        colv = coln;
    }
    a0 += __shfl_xor(a0, 8);           // combine edge halves
    a1 += __shfl_xor(a1, 8);
    {   // self-loop
        H2 p; p.i = s2i[nld * 8 + cd];
        a0 += (float)p.h[0];
        a1 += (float)p.h[1];
    }
    if (n < N && e2 == 0) {
        float di = dinv[nld];
        float2 b = ((const float2*)b2)[cd];
        float2 o;
        o.x = a0 * di + b.x;
        o.y = a1 * di + b.y;
        ((float2*)out)[(size_t)n * 8 + cd] = o;
    }
}

extern "C" void kernel_launch(void* const* d_in, const int* in_sizes, int n_in,
                              void* d_out, int out_size, void* d_ws, size_t ws_size,
                              hipStream_t stream) {
    const int*   x   = (const int*)d_in[0];
    const int*   ei  = (const int*)d_in[1];
    const float* emb = (const float*)d_in[2];
    const float* W1  = (const float*)d_in[3];
    const float* b1  = (const float*)d_in[4];
    const float* W2  = (const float*)d_in[5];
    const float* b2  = (const float*)d_in[6];
    float* out = (float*)d_out;

    const int N = in_sizes[0];
    const int E = in_sizes[1] / 2;
    const int* srcp = ei;
    const int* dstp = ei + E;
    const int NBINS = (N + BIN - 1) >> BINSHIFT;   // 391 for N=100000
    const int L = NBINS * NBLK;
    const int nB2 = (L + BS - 1) / BS;             // == NBINS

    auto al = [](size_t b) { return (b + 255) & ~size_t(255); };
    char* w = (char*)d_ws;
    auto carve = [&](size_t bytes) {
        void* p = (void*)w;
        w += al(bytes);
        return p;
    };
    // no unions: binsort writes sig1 while other blocks still read packed.
    int*   row_start = (int*)carve((size_t)(N + 1) * 4);
    float* dinv      = (float*)carve((size_t)N * 4);
    int*   col       = (int*)carve((size_t)(E + 256) * 4);  // +pad for clamped reads
    int*   histG     = (int*)carve((size_t)L * 4);
    int*   partial   = (int*)carve((size_t)L * 4);
    int*   bsum      = (int*)carve((size_t)nB2 * 4);
    int*   boff      = (int*)carve((size_t)nB2 * 4);
    int*   packed    = (int*)carve((size_t)E * 4);
    _Float16* sig1   = (_Float16*)carve((size_t)N * 32 * 2);
    _Float16* sig2   = (_Float16*)carve((size_t)N * 16 * 2);
    (void)ws_size; (void)n_in; (void)out_size;

    int gL = (L + BS - 1) / BS;
    k_hist<<<NBLK, BSBIG, 0, stream>>>(dstp, E, NBINS, histG);
    k_scanA<<<gL, BS, 0, stream>>>(histG, L, partial, bsum);
    k_binscatter<<<NBLK, BSBIG, 0, stream>>>(srcp, dstp, E, NBINS, nB2, partial,
                                             bsum, boff, packed);
    k_binsort<<<NBINS, BS, 0, stream>>>(packed, partial, boff, NBINS, N, E,
                                        x, emb, W1, row_start, dinv, col, sig1);

    int gA = (N + 15) / 16;            // 4 waves x 4 nodes per block
    k_agg1mm2<<<gA, BS, 0, stream>>>(sig1, row_start, dinv, col, b1, W2, N, sig2);
    k_agg2<<<gA, BS, 0, stream>>>(sig2, row_start, dinv, col, b2, N, out);
}